// Round 3
// baseline (103.796 us; speedup 1.0000x reference)
//
#include <hip/hip_runtime.h>
#include <math.h>

// DetectionLayer: x(32,255,76,76) f32 -> out(32,17328,85) f32
// Block (256 thr) = (b, row i, anchor a, j-chunk of 20 [last=16]).
// LDS = 85ch x PADJ=21 = 7.1KB -> wave-capped 8 blocks/CU (100% occupancy).
// Phase 1: float4-coalesced loads of the 85x20 slab.
// Phase 2: row-per-wave, lane = attr t; stores wave-coalesced; corners
// branchless via one shared __expf + shfl_xor(.,2).

#define NCH   255
#define NATTR 85
#define HW    5776
#define GW    76
#define NBATCH 32
#define PADJ  21
#define BLOCK 256

__global__ __launch_bounds__(BLOCK) void det_kernel(const float* __restrict__ in,
                                                    float* __restrict__ out) {
    // bid = ((b*76 + i)*4 + jc)*3 + a   (a fastest -> contiguous output regions)
    int bid = blockIdx.x;
    int a   = bid % 3;
    int t1  = bid / 3;
    int jc  = t1 & 3;
    int t2  = t1 >> 2;
    int i   = t2 % GW;
    int b   = t2 / GW;
    const int j0    = jc * 20;
    const int width = (jc == 3) ? 16 : 20;

    __shared__ float lds[NATTR * PADJ];

    const float* __restrict__ src =
        in + (size_t)b * (NCH * HW) + (size_t)(a * NATTR) * HW + (size_t)i * GW + j0;

    // ---- phase 1: 85 channels x width cols, float4 loads ----
    if (jc != 3) {
        #pragma unroll 2
        for (int e = threadIdx.x; e < NATTR * 5; e += BLOCK) {
            int c = e / 5, q = e - c * 5;
            float4 v = *(const float4*)(src + (size_t)c * HW + 4 * q);
            float* p = &lds[c * PADJ + 4 * q];
            p[0] = v.x; p[1] = v.y; p[2] = v.z; p[3] = v.w;
        }
    } else {
        #pragma unroll 2
        for (int e = threadIdx.x; e < NATTR * 4; e += BLOCK) {
            int c = e >> 2, q = e & 3;
            float4 v = *(const float4*)(src + (size_t)c * HW + 4 * q);
            float* p = &lds[c * PADJ + 4 * q];
            p[0] = v.x; p[1] = v.y; p[2] = v.z; p[3] = v.w;
        }
    }
    __syncthreads();

    // ---- phase 2: one output row (85 attrs) per wave, lane = t ----
    const int wv = threadIdx.x >> 6;
    const int t  = threadIdx.x & 63;
    const float anc_w = ((a == 0) ? 10.f : (a == 1) ? 16.f : 33.f) * (0.5f / 608.f);
    const float anc_h = ((a == 0) ? 13.f : (a == 1) ? 30.f : 23.f) * (0.5f / 608.f);
    const float fi = (float)i;

    float* __restrict__ dst =
        out + ((size_t)b * 17328 + (size_t)(i * GW + j0) * 3 + a) * NATTR;

    for (int r = wv; r < width; r += 4) {
        const float* rowp = &lds[r];
        float v = rowp[t * PADJ];
        bool iswh = ((t | 1) == 3);               // t==2 || t==3
        float m = iswh ? v : -v;
        float E = __expf(m);
        float s = 1.0f / (1.0f + E);              // sigmoid for non-wh lanes
        float coord = (t & 1) ? fi : (float)(j0 + r);
        float anc   = (t & 1) ? anc_h : anc_w;
        float tmp = (t < 2) ? ((s * 1.05f - 0.025f + coord) * (1.0f / 76.0f))
                            : (E * anc);
        float pp = __shfl_xor(tmp, 2);            // ix<->hw2, iy<->hh2
        float cv = (t < 2) ? (tmp - pp) : (tmp + pp);
        float val = (t < 4) ? cv : s;

        float* drow = dst + (size_t)r * (3 * NATTR);
        drow[t] = val;
        if (t < NATTR - 64) {                     // attrs 64..84 (never corners)
            float v2 = rowp[(t + 64) * PADJ];
            drow[t + 64] = 1.0f / (1.0f + __expf(-v2));
        }
    }
}

extern "C" void kernel_launch(void* const* d_in, const int* in_sizes, int n_in,
                              void* d_out, int out_size, void* d_ws, size_t ws_size,
                              hipStream_t stream) {
    const float* x = (const float*)d_in[0];
    float* out = (float*)d_out;
    int grid = NBATCH * GW * 4 * 3;   // 32*76*4*3 = 29184 blocks
    det_kernel<<<grid, BLOCK, 0, stream>>>(x, out);
}

// Round 4
// 91.430 us; speedup vs baseline: 1.1353x; 1.1353x over previous
//
#include <hip/hip_runtime.h>
#include <math.h>

// DetectionLayer: x(32,255,76,76) f32 -> out(32,17328,85) f32
// Block (512 thr) = (b, row i, anchor a). LDS [85ch][77] = 26.2KB
// -> 4 blocks/CU (wave-capped) = 100% theoretical occupancy.
// Phase 1: full-row float4 loads (19 per channel, all 16B-aligned).
// Phase 2a: non-corner attrs (t>=4), block-raster, coalesced stores,
//           stride-77 LDS reads (77%32=13 coprime -> conflict-free).
// Phase 2b: 304 corner elems in a separate small pass (avoids dragging
//           the 2-expf corner path into the hot loop via if-conversion).
// XCD-chunked bid swizzle (7296%8==0 -> simple form bijective).

#define NCH    255
#define NATTR  85
#define HW     5776
#define GW     76
#define NBATCH 32
#define PADJ   77
#define BLOCK  512
#define NWG    (NBATCH * 3 * GW)   // 7296

__device__ __forceinline__ float sigm(float x) {
    return __builtin_amdgcn_rcpf(1.0f + __expf(-x));
}

__global__ __launch_bounds__(BLOCK) void det_kernel(const float* __restrict__ in,
                                                    float* __restrict__ out) {
    // XCD-aware swizzle: hw-consecutive bids round-robin XCDs; give each XCD
    // a contiguous chunk of logical order (b, a, i) with i fastest.
    int hw = blockIdx.x;
    int L  = (hw & 7) * (NWG / 8) + (hw >> 3);
    int i  = L % GW;
    int ba = L / GW;
    int a  = ba % 3;
    int b  = ba / 3;

    __shared__ float lds[NATTR * PADJ];

    const float* __restrict__ src =
        in + (size_t)(b * NCH + a * NATTR) * HW + (size_t)i * GW;

    // ---- phase 1: 85 channels x 76 cols, 19 float4 per channel ----
    #pragma unroll 2
    for (int e = threadIdx.x; e < NATTR * 19; e += BLOCK) {
        int c = e / 19, q = e - c * 19;
        float4 v = *(const float4*)(src + (size_t)c * HW + 4 * q);
        float* p = &lds[c * PADJ + 4 * q];
        p[0] = v.x; p[1] = v.y; p[2] = v.z; p[3] = v.w;
    }
    __syncthreads();

    const float anc_w = ((a == 0) ? 10.f : (a == 1) ? 16.f : 33.f) * (0.5f / 608.f);
    const float anc_h = ((a == 0) ? 13.f : (a == 1) ? 30.f : 23.f) * (0.5f / 608.f);
    const float fi = (float)i;

    // block's output region: rows j=0..75 at (i*76+j)*3 + a, each 85 floats
    float* __restrict__ dst =
        out + ((size_t)b * 17328 + (size_t)i * (GW * 3) + a) * NATTR;

    // ---- phase 2b: corners (j,t<4): 304 elems ----
    for (int e = threadIdx.x; e < GW * 4; e += BLOCK) {
        int r = e >> 2;          // col j
        int t = e & 3;
        float ixy, hwh;
        if (t & 1) {             // y: needs a1, a3
            float a1 = lds[1 * PADJ + r], a3 = lds[3 * PADJ + r];
            ixy = (sigm(a1) * 1.05f - 0.025f + fi) * (1.0f / 76.0f);
            hwh = __expf(a3) * anc_h;
        } else {                 // x: needs a0, a2
            float a0 = lds[0 * PADJ + r], a2 = lds[2 * PADJ + r];
            ixy = (sigm(a0) * 1.05f - 0.025f + (float)r) * (1.0f / 76.0f);
            hwh = __expf(a2) * anc_w;
        }
        dst[(size_t)r * (3 * NATTR) + t] = (t < 2) ? (ixy - hwh) : (ixy + hwh);
    }

    // ---- phase 2a: t in [4,85): 76*81 = 6156 elems, plain sigmoid ----
    #pragma unroll 2
    for (int e = threadIdx.x; e < GW * 81; e += BLOCK) {
        int r = e / 81;
        int t = e - r * 81 + 4;
        float v = lds[t * PADJ + r];
        dst[(size_t)r * (3 * NATTR) + t] = sigm(v);
    }
}

extern "C" void kernel_launch(void* const* d_in, const int* in_sizes, int n_in,
                              void* d_out, int out_size, void* d_ws, size_t ws_size,
                              hipStream_t stream) {
    const float* x = (const float*)d_in[0];
    float* out = (float*)d_out;
    det_kernel<<<NWG, BLOCK, 0, stream>>>(x, out);
}